// Round 4
// baseline (57.989 us; speedup 1.0000x reference)
//
#include <hip/hip_runtime.h>
#include <math.h>

typedef float vf4 __attribute__((ext_vector_type(4)));

__device__ __forceinline__ float wave_reduce_sum(float v) {
    #pragma unroll
    for (int off = 32; off > 0; off >>= 1)
        v += __shfl_xor(v, off, 64);
    return v;
}
__device__ __forceinline__ float wave_reduce_max(float v) {
    #pragma unroll
    for (int off = 32; off > 0; off >>= 1)
        v = fmaxf(v, __shfl_xor(v, off, 64));
    return v;
}

// fast tanh: tanh(x) = 1 - 2/(exp(2x)+1); exp via v_exp, recip via v_rcp
__device__ __forceinline__ float fast_tanh(float x) {
    float e = __expf(2.0f * x);
    return 1.0f - 2.0f * __builtin_amdgcn_rcpf(e + 1.0f);
}

// Kernel 1: rec[b*H + h] = dot(rnn_state[b,:], W_rec[h,:])
// One wave per output element; lanes split R with float4 loads.
__global__ void rec_kernel(const float* __restrict__ rnn,
                           const float* __restrict__ Wrec,
                           float* __restrict__ rec,
                           int B, int H, int R) {
    int w    = (blockIdx.x * blockDim.x + threadIdx.x) >> 6;
    int lane = threadIdx.x & 63;
    int nOut = B * H;
    if (w >= nOut) return;
    int b = w / H;
    int h = w - b * H;
    const float* xr = rnn  + (size_t)b * R;
    const float* wr = Wrec + (size_t)h * R;
    float acc = 0.f;
    for (int r = lane * 4; r < R; r += 256) {
        vf4 a = *(const vf4*)(xr + r);
        vf4 c = *(const vf4*)(wr + r);
        acc += a.x * c.x + a.y * c.y + a.z * c.z + a.w * c.w;
    }
    acc = wave_reduce_sum(acc);
    if (lane == 0) rec[w] = acc;
}

// Kernel 2: each wave owns a fixed b and SCORE_ROWS consecutive t values.
// rec row + w_score live in registers; the row loop is ROLLED with a 2-deep
// explicit prefetch so live VGPR stays under 64 -> 8 blocks/CU -> 32 waves/CU.
// Latency hiding comes from TLP, not unroll.
#define SCORE_ROWS 16
__global__ void __launch_bounds__(256, 8)
score_kernel(const float* __restrict__ enc,
             const float* __restrict__ mask,
             const float* __restrict__ rec,
             const float* __restrict__ wsc,
             const float* __restrict__ bsc,
             float* __restrict__ scores_t,  // (B,T)
             int T, int B, int H) {
    const int w    = (blockIdx.x * blockDim.x + threadIdx.x) >> 6;
    const int lane = threadIdx.x & 63;
    const int b     = w % B;
    const int tbase = (w / B) * SCORE_ROWS;
    if (tbase >= T) return;

    const int h0 = lane * 4;          // first half: h in [0, H/2)
    const int h1 = (H >> 1) + h0;     // second half

    // per-lane invariant operands (8 floats each), loaded once
    const float* rr = rec + (size_t)b * H;
    vf4 r0 = *(const vf4*)(rr + h0);
    vf4 r1 = *(const vf4*)(rr + h1);
    vf4 w0 = *(const vf4*)(wsc + h0);
    vf4 w1 = *(const vf4*)(wsc + h1);
    const float bias = bsc[0];

    const float* erow = enc + ((size_t)tbase * B + b) * H;
    const size_t rstride = (size_t)B * H;

    // prefetch row 0
    vf4 a0 = __builtin_nontemporal_load((const vf4*)(erow + h0));
    vf4 a1 = __builtin_nontemporal_load((const vf4*)(erow + h1));

    #pragma unroll 1
    for (int i = 0; i < SCORE_ROWS - 1; ++i) {
        const float* ern = erow + (size_t)(i + 1) * rstride;
        vf4 n0 = __builtin_nontemporal_load((const vf4*)(ern + h0));
        vf4 n1 = __builtin_nontemporal_load((const vf4*)(ern + h1));

        float acc;
        acc  = w0.x * fast_tanh(a0.x + r0.x);
        acc += w0.y * fast_tanh(a0.y + r0.y);
        acc += w0.z * fast_tanh(a0.z + r0.z);
        acc += w0.w * fast_tanh(a0.w + r0.w);
        acc += w1.x * fast_tanh(a1.x + r1.x);
        acc += w1.y * fast_tanh(a1.y + r1.y);
        acc += w1.z * fast_tanh(a1.z + r1.z);
        acc += w1.w * fast_tanh(a1.w + r1.w);
        acc = wave_reduce_sum(acc);
        if (lane == 0) {
            const int t = tbase + i;
            scores_t[(size_t)b * T + t] = acc + bias + mask[(size_t)t * B + b];
        }
        a0 = n0; a1 = n1;
    }
    // last row
    {
        float acc;
        acc  = w0.x * fast_tanh(a0.x + r0.x);
        acc += w0.y * fast_tanh(a0.y + r0.y);
        acc += w0.z * fast_tanh(a0.z + r0.z);
        acc += w0.w * fast_tanh(a0.w + r0.w);
        acc += w1.x * fast_tanh(a1.x + r1.x);
        acc += w1.y * fast_tanh(a1.y + r1.y);
        acc += w1.z * fast_tanh(a1.z + r1.z);
        acc += w1.w * fast_tanh(a1.w + r1.w);
        acc = wave_reduce_sum(acc);
        if (lane == 0) {
            const int t = tbase + SCORE_ROWS - 1;
            scores_t[(size_t)b * T + t] = acc + bias + mask[(size_t)t * B + b];
        }
    }
}

// Kernel 3: softmax over T per column b. One block (T/4 threads) per b.
// Coalesced float4 read from (B,T) scores; scattered 4B writes to (T,B) out.
__global__ void softmax_kernel(const float* __restrict__ scores_t,
                               float* __restrict__ out, int T, int B) {
    const int b    = blockIdx.x;
    const int tid  = threadIdx.x;
    const int wid  = tid >> 6;
    const int lane = tid & 63;
    const int nw   = blockDim.x >> 6;

    vf4 v = *(const vf4*)(scores_t + (size_t)b * T + tid * 4);

    __shared__ float red[16];

    float m = fmaxf(fmaxf(v.x, v.y), fmaxf(v.z, v.w));
    m = wave_reduce_max(m);
    if (lane == 0) red[wid] = m;
    __syncthreads();
    if (tid < 64) {
        float mm = (tid < nw) ? red[tid] : -INFINITY;
        mm = wave_reduce_max(mm);
        if (tid == 0) red[0] = mm;
    }
    __syncthreads();
    m = red[0];
    __syncthreads();                 // everyone has read red[0]

    v.x = __expf(v.x - m);
    v.y = __expf(v.y - m);
    v.z = __expf(v.z - m);
    v.w = __expf(v.w - m);
    float s = (v.x + v.y) + (v.z + v.w);
    s = wave_reduce_sum(s);
    if (lane == 0) red[wid] = s;
    __syncthreads();
    if (tid < 64) {
        float ss = (tid < nw) ? red[tid] : 0.f;
        ss = wave_reduce_sum(ss);
        if (tid == 0) red[0] = ss;
    }
    __syncthreads();
    const float inv = 1.0f / red[0];

    const int t0 = tid * 4;
    out[(size_t)(t0 + 0) * B + b] = v.x * inv;
    out[(size_t)(t0 + 1) * B + b] = v.y * inv;
    out[(size_t)(t0 + 2) * B + b] = v.z * inv;
    out[(size_t)(t0 + 3) * B + b] = v.w * inv;
}

extern "C" void kernel_launch(void* const* d_in, const int* in_sizes, int n_in,
                              void* d_out, int out_size, void* d_ws, size_t ws_size,
                              hipStream_t stream) {
    const float* enc  = (const float*)d_in[0];  // (T,B,H)
    const float* mask = (const float*)d_in[1];  // (T,B)
    const float* rnn  = (const float*)d_in[2];  // (B,R)
    // d_in[3] = prev_att_weights, unused by the reference
    const float* Wrec = (const float*)d_in[4];  // (H,R)
    const float* wsc  = (const float*)d_in[5];  // (H,)
    const float* bsc  = (const float*)d_in[6];  // (1,)

    const int H = in_sizes[5];
    const int R = in_sizes[4] / H;
    const int B = in_sizes[2] / R;
    const int T = in_sizes[1] / B;

    float* rec      = (float*)d_ws;                  // B*H floats (64 KB)
    float* scores_t = (float*)d_ws + (size_t)B * H;  // (B,T) floats (512 KB)
    float* out      = (float*)d_out;                 // (T,B)

    // Kernel 1: B*H outputs, one wave each, 4 waves per 256-thread block
    {
        int nOut   = B * H;
        int blocks = (nOut + 3) / 4;
        rec_kernel<<<blocks, 256, 0, stream>>>(rnn, Wrec, rec, B, H, R);
    }
    // Kernel 2: one wave per (b, 16-row strip): T*B/16 waves
    {
        int nWaves = (T / SCORE_ROWS) * B;
        int blocks = (nWaves + 3) / 4;
        score_kernel<<<blocks, 256, 0, stream>>>(enc, mask, rec, wsc, bsc,
                                                 scores_t, T, B, H);
    }
    // Kernel 3: one block per b, T/4 threads (T=4096 -> 1024)
    softmax_kernel<<<B, T / 4, 0, stream>>>(scores_t, out, T, B);
}

// Round 5
// 55.757 us; speedup vs baseline: 1.0400x; 1.0400x over previous
//
#include <hip/hip_runtime.h>
#include <math.h>

typedef float vf4 __attribute__((ext_vector_type(4)));

__device__ __forceinline__ float wave_reduce_sum(float v) {
    #pragma unroll
    for (int off = 32; off > 0; off >>= 1)
        v += __shfl_xor(v, off, 64);
    return v;
}
__device__ __forceinline__ float wave_reduce_max(float v) {
    #pragma unroll
    for (int off = 32; off > 0; off >>= 1)
        v = fmaxf(v, __shfl_xor(v, off, 64));
    return v;
}

// fast tanh: tanh(x) = 1 - 2/(exp(2x)+1); exp via v_exp, recip via v_rcp
__device__ __forceinline__ float fast_tanh(float x) {
    float e = __expf(2.0f * x);
    return 1.0f - 2.0f * __builtin_amdgcn_rcpf(e + 1.0f);
}

// Kernel 1: rec[b*H + h] = dot(rnn_state[b,:], W_rec[h,:])
// One wave per output element; lanes split R with float4 loads.
__global__ void rec_kernel(const float* __restrict__ rnn,
                           const float* __restrict__ Wrec,
                           float* __restrict__ rec,
                           int B, int H, int R) {
    int w    = (blockIdx.x * blockDim.x + threadIdx.x) >> 6;
    int lane = threadIdx.x & 63;
    int nOut = B * H;
    if (w >= nOut) return;
    int b = w / H;
    int h = w - b * H;
    const float* xr = rnn  + (size_t)b * R;
    const float* wr = Wrec + (size_t)h * R;
    float acc = 0.f;
    for (int r = lane * 4; r < R; r += 256) {
        vf4 a = *(const vf4*)(xr + r);
        vf4 c = *(const vf4*)(wr + r);
        acc += a.x * c.x + a.y * c.y + a.z * c.z + a.w * c.w;
    }
    acc = wave_reduce_sum(acc);
    if (lane == 0) rec[w] = acc;
}

// Kernel 2: each wave owns a fixed b and SCORE_ROWS consecutive t values.
// Per-row partials accumulate into acc[16]; ONE batched tree-reduce per strip
// (17 shfls total) replaces 16 serial 6-step butterflies. After the 4 fold
// stages, lane l holds the partial for row (l&15) summed over its 16-lane
// group; two butterflies (xor 16,32) finish the 64-lane sum. Lanes 0..15 then
// do one coalesced 16-lane store (and one parallel mask gather).
#define SCORE_ROWS 16
__global__ void score_kernel(const float* __restrict__ enc,
                             const float* __restrict__ mask,
                             const float* __restrict__ rec,
                             const float* __restrict__ wsc,
                             const float* __restrict__ bsc,
                             float* __restrict__ scores_t,  // (B,T)
                             int T, int B, int H) {
    const int w    = (blockIdx.x * blockDim.x + threadIdx.x) >> 6;
    const int lane = threadIdx.x & 63;
    const int b     = w % B;
    const int tbase = (w / B) * SCORE_ROWS;
    if (tbase >= T) return;

    const int h0 = lane * 4;          // first half: h in [0, H/2)
    const int h1 = (H >> 1) + h0;     // second half

    // per-lane invariant operands (8 floats each), loaded once
    const float* rr = rec + (size_t)b * H;
    vf4 r0 = *(const vf4*)(rr + h0);
    vf4 r1 = *(const vf4*)(rr + h1);
    vf4 w0 = *(const vf4*)(wsc + h0);
    vf4 w1 = *(const vf4*)(wsc + h1);
    const float bias = bsc[0];

    const float* erow = enc + ((size_t)tbase * B + b) * H;
    const size_t rstride = (size_t)B * H;

    float acc[SCORE_ROWS];
    #pragma unroll
    for (int i = 0; i < SCORE_ROWS; ++i) {
        const float* er = erow + (size_t)i * rstride;
        vf4 e0 = *(const vf4*)(er + h0);
        vf4 e1 = *(const vf4*)(er + h1);
        float a;
        a  = w0.x * fast_tanh(e0.x + r0.x);
        a += w0.y * fast_tanh(e0.y + r0.y);
        a += w0.z * fast_tanh(e0.z + r0.z);
        a += w0.w * fast_tanh(e0.w + r0.w);
        a += w1.x * fast_tanh(e1.x + r1.x);
        a += w1.y * fast_tanh(e1.y + r1.y);
        a += w1.z * fast_tanh(e1.z + r1.z);
        a += w1.w * fast_tanh(e1.w + r1.w);
        acc[i] = a;
    }

    // fold stages: value count 16 -> 8 -> 4 -> 2 -> 1 across lane bits 0..3
    #pragma unroll
    for (int s = 0; s < 4; ++s) {
        const int bit = 1 << s;
        #pragma unroll
        for (int i = 0; i < (SCORE_ROWS >> (s + 1)); ++i) {
            float sent = (lane & bit) ? acc[2 * i]     : acc[2 * i + 1];
            float keep = (lane & bit) ? acc[2 * i + 1] : acc[2 * i];
            acc[i] = keep + __shfl_xor(sent, bit, 64);
        }
    }
    // finish the 64-lane sum: lane l now owns row (l&15)
    acc[0] += __shfl_xor(acc[0], 16, 64);
    acc[0] += __shfl_xor(acc[0], 32, 64);

    if (lane < SCORE_ROWS) {
        const int t = tbase + lane;
        scores_t[(size_t)b * T + t] = acc[0] + bias + mask[(size_t)t * B + b];
    }
}

// Kernel 3: softmax over T per column b. One block (T/4 threads) per b.
// Coalesced float4 read from (B,T) scores; scattered 4B writes to (T,B) out.
__global__ void softmax_kernel(const float* __restrict__ scores_t,
                               float* __restrict__ out, int T, int B) {
    const int b    = blockIdx.x;
    const int tid  = threadIdx.x;
    const int wid  = tid >> 6;
    const int lane = tid & 63;
    const int nw   = blockDim.x >> 6;

    vf4 v = *(const vf4*)(scores_t + (size_t)b * T + tid * 4);

    __shared__ float red[16];

    float m = fmaxf(fmaxf(v.x, v.y), fmaxf(v.z, v.w));
    m = wave_reduce_max(m);
    if (lane == 0) red[wid] = m;
    __syncthreads();
    if (tid < 64) {
        float mm = (tid < nw) ? red[tid] : -INFINITY;
        mm = wave_reduce_max(mm);
        if (tid == 0) red[0] = mm;
    }
    __syncthreads();
    m = red[0];
    __syncthreads();                 // everyone has read red[0]

    v.x = __expf(v.x - m);
    v.y = __expf(v.y - m);
    v.z = __expf(v.z - m);
    v.w = __expf(v.w - m);
    float s = (v.x + v.y) + (v.z + v.w);
    s = wave_reduce_sum(s);
    if (lane == 0) red[wid] = s;
    __syncthreads();
    if (tid < 64) {
        float ss = (tid < nw) ? red[tid] : 0.f;
        ss = wave_reduce_sum(ss);
        if (tid == 0) red[0] = ss;
    }
    __syncthreads();
    const float inv = 1.0f / red[0];

    const int t0 = tid * 4;
    out[(size_t)(t0 + 0) * B + b] = v.x * inv;
    out[(size_t)(t0 + 1) * B + b] = v.y * inv;
    out[(size_t)(t0 + 2) * B + b] = v.z * inv;
    out[(size_t)(t0 + 3) * B + b] = v.w * inv;
}

extern "C" void kernel_launch(void* const* d_in, const int* in_sizes, int n_in,
                              void* d_out, int out_size, void* d_ws, size_t ws_size,
                              hipStream_t stream) {
    const float* enc  = (const float*)d_in[0];  // (T,B,H)
    const float* mask = (const float*)d_in[1];  // (T,B)
    const float* rnn  = (const float*)d_in[2];  // (B,R)
    // d_in[3] = prev_att_weights, unused by the reference
    const float* Wrec = (const float*)d_in[4];  // (H,R)
    const float* wsc  = (const float*)d_in[5];  // (H,)
    const float* bsc  = (const float*)d_in[6];  // (1,)

    const int H = in_sizes[5];
    const int R = in_sizes[4] / H;
    const int B = in_sizes[2] / R;
    const int T = in_sizes[1] / B;

    float* rec      = (float*)d_ws;                  // B*H floats (64 KB)
    float* scores_t = (float*)d_ws + (size_t)B * H;  // (B,T) floats (512 KB)
    float* out      = (float*)d_out;                 // (T,B)

    // Kernel 1: B*H outputs, one wave each, 4 waves per 256-thread block
    {
        int nOut   = B * H;
        int blocks = (nOut + 3) / 4;
        rec_kernel<<<blocks, 256, 0, stream>>>(rnn, Wrec, rec, B, H, R);
    }
    // Kernel 2: one wave per (b, 16-row strip): T*B/16 waves
    {
        int nWaves = (T / SCORE_ROWS) * B;
        int blocks = (nWaves + 3) / 4;
        score_kernel<<<blocks, 256, 0, stream>>>(enc, mask, rec, wsc, bsc,
                                                 scores_t, T, B, H);
    }
    // Kernel 3: one block per b, T/4 threads (T=4096 -> 1024)
    softmax_kernel<<<B, T / 4, 0, stream>>>(scores_t, out, T, B);
}